// Round 12
// baseline (78.059 us; speedup 1.0000x reference)
//
#include <hip/hip_runtime.h>
#include <hip/hip_bf16.h>
#include <stdint.h>

// Problem: B=16, S=1024, IN=1024, OUT=1024.
// Reference collapses: softmax row-sums are exactly 1 (key mask always has >=1
// live column), so out = leaky_relu(xs @ (Wlin@Wv)^T + (Wlin@bv + blin)).
//
// Round 12: main GEMM plateaued at ~740 TF across 7 schedule variants ->
// eliminate the prep tax instead. prep1 (xs->bf16 pass, ~96MB traffic) is
// deleted; the fp32->bf16 A conversion is fused into round-10's proven
// 4-buffer counted-vmcnt ring with the measured-zero-conflict row-pair
// swz128 LDS geometry. A: 4 float4 loads (tile T+2) at phase-A top, cvt +
// linear ds_write after phase-B MFMA. B: gload_lds depth-3 from L2-hot Wc.

#define M_TOT 16384   // B*S
#define KDIM  1024
#define NDIM  1024
#define NT    32      // K-tiles of BK=32 in main GEMM

typedef __attribute__((ext_vector_type(8))) short bf16x8;
typedef __attribute__((ext_vector_type(4))) float f32x4;
typedef __attribute__((ext_vector_type(4))) unsigned short u16x4;
typedef __attribute__((ext_vector_type(8))) unsigned short u16x8;

static __device__ __forceinline__ unsigned short f2bf(float f) {
    union { float f; unsigned int u; } v; v.f = f;
    unsigned int u = v.u;
    return (unsigned short)((u + 0x7fffu + ((u >> 16) & 1u)) >> 16);  // RNE
}

static __device__ __forceinline__ u16x8 pack8(float4 a, float4 b) {
    u16x8 p = { f2bf(a.x), f2bf(a.y), f2bf(a.z), f2bf(a.w),
                f2bf(b.x), f2bf(b.y), f2bf(b.z), f2bf(b.w) };
    return p;
}

static __device__ __forceinline__ void gload16(const void* g, void* l) {
    __builtin_amdgcn_global_load_lds(
        (__attribute__((address_space(1))) void*)(g),
        (__attribute__((address_space(3))) void*)(l), 16, 0, 0);
}

// Involutive byte-swizzle for 128B-row LDS tiles: XOR row bits (7-9) into
// 16B-slot bits (4-6). Measured 0 bank conflicts (rounds 5-7, 10, 11).
static __device__ __forceinline__ int swz128(int p) {
    return p ^ (((p >> 7) & 7) << 4);
}

// ---------------------------------------------------------------------------
// prep0: [0,256) transpose Wv[d][i] -> Wvt[i][d] bf16 (64x64 tiles, padded
//        fp32 LDS); [256,512) Wlin -> Wlb bf16; [512,768) bias fold.
// ---------------------------------------------------------------------------
__global__ __launch_bounds__(256) void prep0_kernel(
    const float* __restrict__ Wv, const float* __restrict__ Wlin,
    const float* __restrict__ bv, const float* __restrict__ blin,
    unsigned short* __restrict__ Wvt, unsigned short* __restrict__ Wlb,
    float* __restrict__ bcomb) {
    __shared__ float Tl[64 * 65];
    const int bid = blockIdx.x;
    const int t = threadIdx.x;

    if (bid < 256) {
        const int dt = bid >> 4;
        const int it = bid & 15;
        const int r = t >> 2;
        const int c0 = (t & 3) * 16;
        #pragma unroll
        for (int u = 0; u < 4; ++u) {
            float4 v = *(const float4*)&Wv[((size_t)(dt * 64 + r)) * NDIM + it * 64 + c0 + 4 * u];
            Tl[r * 65 + c0 + 4 * u + 0] = v.x;
            Tl[r * 65 + c0 + 4 * u + 1] = v.y;
            Tl[r * 65 + c0 + 4 * u + 2] = v.z;
            Tl[r * 65 + c0 + 4 * u + 3] = v.w;
        }
        __syncthreads();
        const int i = t >> 2;
        const int dq = (t & 3) * 16;
        float v[16];
        #pragma unroll
        for (int u = 0; u < 16; ++u) v[u] = Tl[(dq + u) * 65 + i];
        u16x8 p0 = { f2bf(v[0]), f2bf(v[1]), f2bf(v[2]), f2bf(v[3]),
                     f2bf(v[4]), f2bf(v[5]), f2bf(v[6]), f2bf(v[7]) };
        u16x8 p1 = { f2bf(v[8]), f2bf(v[9]), f2bf(v[10]), f2bf(v[11]),
                     f2bf(v[12]), f2bf(v[13]), f2bf(v[14]), f2bf(v[15]) };
        unsigned short* dst = &Wvt[((size_t)(it * 64 + i)) * KDIM + dt * 64 + dq];
        *(u16x8*)dst = p0;
        *(u16x8*)(dst + 8) = p1;
    } else if (bid < 512) {
        const size_t idx = (((size_t)(bid - 256)) * 256 + t) * 16;
        float4 a = *(const float4*)&Wlin[idx];
        float4 b = *(const float4*)&Wlin[idx + 4];
        float4 c = *(const float4*)&Wlin[idx + 8];
        float4 d = *(const float4*)&Wlin[idx + 12];
        *(u16x8*)&Wlb[idx] = pack8(a, b);
        *(u16x8*)&Wlb[idx + 8] = pack8(c, d);
    } else {
        const int wave = t >> 6, lane = t & 63;
        const int o = (bid - 512) * 4 + wave;
        float s = 0.f;
        for (int d = lane; d < KDIM; d += 64) s += Wlin[o * KDIM + d] * bv[d];
        #pragma unroll
        for (int off = 32; off > 0; off >>= 1) s += __shfl_down(s, off, 64);
        if (lane == 0) bcomb[o] = s + blin[o];
    }
}

// ---------------------------------------------------------------------------
// wcomb: Wc[o][i] = sum_d Wlb[o][d] * Wvt[i][d]. 64x64 tiles, 256 blocks,
// 4 waves (2x2 of 32x32), both operands via global_load_lds.
// ---------------------------------------------------------------------------
__global__ __launch_bounds__(256) void wcomb_kernel(
    const unsigned short* __restrict__ Wlb, const unsigned short* __restrict__ Wvt,
    unsigned short* __restrict__ Wc) {
    __shared__ unsigned short As[64 * 32];
    __shared__ unsigned short Bs[64 * 32];
    const int t = threadIdx.x;
    const int ot = blockIdx.x >> 4;
    const int it = blockIdx.x & 15;
    const int w = t >> 6, l = t & 63;
    const int wr = (w >> 1) * 32, wc = (w & 1) * 32;
    const int lr = l & 15, lk = l >> 4;

    f32x4 acc[2][2] = {};

    const unsigned short* gA = &Wlb[((size_t)(ot * 64 + (t >> 2))) * KDIM + (t & 3) * 8];
    const unsigned short* gB = &Wvt[((size_t)(it * 64 + (t >> 2))) * KDIM + (t & 3) * 8];
    unsigned short* lA = &As[w * 512];
    unsigned short* lB = &Bs[w * 512];

    for (int kt = 0; kt < KDIM / 32; ++kt) {
        gload16(gA + kt * 32, lA);
        gload16(gB + kt * 32, lB);
        __syncthreads();
        bf16x8 af[2], bfr[2];
        #pragma unroll
        for (int fi = 0; fi < 2; ++fi)
            af[fi] = *(bf16x8*)&As[(wr + fi * 16 + lr) * 32 + lk * 8];
        #pragma unroll
        for (int fj = 0; fj < 2; ++fj)
            bfr[fj] = *(bf16x8*)&Bs[(wc + fj * 16 + lr) * 32 + lk * 8];
        #pragma unroll
        for (int fi = 0; fi < 2; ++fi)
            #pragma unroll
            for (int fj = 0; fj < 2; ++fj)
                acc[fi][fj] = __builtin_amdgcn_mfma_f32_16x16x32_bf16(
                    af[fi], bfr[fj], acc[fi][fj], 0, 0, 0);
        __syncthreads();
    }
    #pragma unroll
    for (int fi = 0; fi < 2; ++fi)
        #pragma unroll
        for (int fj = 0; fj < 2; ++fj)
            #pragma unroll
            for (int r = 0; r < 4; ++r) {
                const int o = ot * 64 + wr + fi * 16 + lk * 4 + r;
                const int i = it * 64 + wc + fj * 16 + lr;
                Wc[(size_t)o * KDIM + i] = f2bf(acc[fi][fj][r]);
            }
}

// ---------------------------------------------------------------------------
// main_fused: out = leaky(bf16(xs) @ Wc^T + bcomb), A converted in-kernel.
// Round-10 schedule: BM=BN=256, BK=32, 8 waves (2Mx4N), 4-buffer LDS ring
// (4 x 32KB: A [256][32]bf16 row-pair swz128 @0, B @16384), counted vmcnt,
// 2 phases/tile, setprio, plain barriers, bijective XCD swizzle, grid 256.
// A path (new): 4 float4 xs loads for tile T+2 at phase-A top; cvt + 2
// linear ds_write_b128 (inverse-swizzled content) after phase-B MFMA.
// B path: gload_lds depth-3 from pre-swizzled Wc source (L2-resident).
// Boundary: vmcnt(2) + lgkmcnt(0) + barrier (cvt's implicit A-wait already
// drains everything older than B(T+3)).
// ---------------------------------------------------------------------------
__global__ __launch_bounds__(512, 2) void main_fused(
    const float* __restrict__ xs, const unsigned short* __restrict__ Wc,
    const float* __restrict__ bcomb, float* __restrict__ out) {
    extern __shared__ char lds[];  // 131072
    const int tid = threadIdx.x;
    const int w = tid >> 6, l = tid & 63;
    const int wm = w >> 2, wn = w & 3;
    const int lr = l & 15, lk = l >> 4;

    // XCD swizzle (256 % 8 == 0, bijective)
    const int swzb = ((blockIdx.x & 7) << 5) + (blockIdx.x >> 3);
    const int mt = swzb >> 2, nt = swzb & 3;

    // reader LDS byte offsets (row-pair packing P(r,k)=(r>>1)*128+(r&1)*64+k*2)
    int aoff[8], boff[4];
    #pragma unroll
    for (int fi = 0; fi < 8; ++fi) {
        const int r = wm * 128 + fi * 16 + lr;
        aoff[fi] = swz128(((r >> 1) << 7) | ((r & 1) << 6) | (lk << 4));
    }
    #pragma unroll
    for (int fj = 0; fj < 4; ++fj) {
        const int r = wn * 64 + fj * 16 + lr;
        boff[fj] = 16384 + swz128(((r >> 1) << 7) | ((r & 1) << 6) | (lk << 4));
    }

    // A staging (fp32 source, reg cvt): thread t fills linear bytes
    // q = c*8192 + t*16 (c in {0,1}); content = logical byte p = swz128(q).
    const float* gAq[2];
    #pragma unroll
    for (int c = 0; c < 2; ++c) {
        const int q = c * 8192 + tid * 16;
        const int p = swz128(q);
        const int r = ((p >> 7) << 1) | ((p >> 6) & 1);
        gAq[c] = xs + ((size_t)(mt * 256 + r)) * KDIM + ((p & 63) >> 1);
    }
    const int ldsA0 = tid * 16;
    const int ldsA1 = 8192 + tid * 16;

    // B staging: per-lane pre-swizzled global source, linear gload_lds dest.
    const char* srcB0; const char* srcB1;
    {
        const int q0 = 0 * 8192 + w * 1024 + l * 16, p0 = swz128(q0);
        const int q1 = 1 * 8192 + w * 1024 + l * 16, p1 = swz128(q1);
        const int r0 = ((p0 >> 7) << 1) | ((p0 >> 6) & 1), c0 = p0 & 63;
        const int r1 = ((p1 >> 7) << 1) | ((p1 >> 6) & 1), c1 = p1 & 63;
        srcB0 = (const char*)Wc + ((size_t)(nt * 256 + r0) * KDIM) * 2 + c0;
        srcB1 = (const char*)Wc + ((size_t)(nt * 256 + r1) * KDIM) * 2 + c1;
    }
    const int ldsw = w * 1024;

    f32x4 acc[8][4] = {};
    float4 avA[4];

#define LOAD_A(TT)                                                             \
    do {                                                                       \
        avA[0] = *(const float4*)(gAq[0] + (TT) * 32);                         \
        avA[1] = *(const float4*)(gAq[0] + (TT) * 32 + 4);                     \
        avA[2] = *(const float4*)(gAq[1] + (TT) * 32);                         \
        avA[3] = *(const float4*)(gAq[1] + (TT) * 32 + 4);                     \
    } while (0)

#define CVT_A(BUF)                                                             \
    do {                                                                       \
        *(u16x8*)((BUF) + ldsA0) = pack8(avA[0], avA[1]);                      \
        *(u16x8*)((BUF) + ldsA1) = pack8(avA[2], avA[3]);                      \
    } while (0)

#define GLOAD_B(TT, BUF)                                                       \
    do {                                                                       \
        gload16(srcB0 + (size_t)(TT) * 64, (BUF) + 16384 + ldsw);              \
        gload16(srcB1 + (size_t)(TT) * 64, (BUF) + 24576 + ldsw);              \
    } while (0)

    // prologue: A(0),A(1) cvt'd into buf0/buf1; B(0..2) gloaded into buf0-2.
    LOAD_A(0);
    CVT_A(lds);                        // implicit wait on A(0) regs
    LOAD_A(1);
    CVT_A(lds + 32768);                // implicit wait on A(1) regs
    GLOAD_B(0, lds);
    GLOAD_B(1, lds + 32768);
    GLOAD_B(2, lds + 65536);
    asm volatile("s_waitcnt vmcnt(4)" ::: "memory");   // B(0) resident
    asm volatile("s_waitcnt lgkmcnt(0)" ::: "memory");
    __builtin_amdgcn_s_barrier();

#define MFMA16(ACCI, AF, BF)                                                   \
    _Pragma("unroll")                                                          \
    for (int fi = 0; fi < 4; ++fi)                                             \
        _Pragma("unroll")                                                      \
        for (int fj = 0; fj < 4; ++fj)                                         \
            acc[(ACCI) + fi][fj] = __builtin_amdgcn_mfma_f32_16x16x32_bf16(    \
                (AF)[fi], (BF)[fj], acc[(ACCI) + fi][fj], 0, 0, 0)

    // KTILE T: compute from buf[T&3]; SA: A(T+2) (load P-A top, cvt P-B end
    // into buf[(T+2)&3] A region); SB: B(T+3) gload into buf[(T+3)&3].
#define KTILE(T, SA, SB, WN)                                                   \
    do {                                                                       \
        const char* cbuf = lds + (size_t)((T) & 3) * 32768;                    \
        char* abuf = lds + (size_t)(((T) + 2) & 3) * 32768;                    \
        char* bbuf = lds + (size_t)(((T) + 3) & 3) * 32768;                    \
        /* phase A: issue A(T+2) reg loads; read B frags + low A frags */      \
        if (SA) { LOAD_A((T) + 2); }                                           \
        bf16x8 bfr[4], afr[4];                                                 \
        _Pragma("unroll")                                                      \
        for (int fj = 0; fj < 4; ++fj)                                         \
            bfr[fj] = *(const bf16x8*)(cbuf + boff[fj]);                       \
        _Pragma("unroll")                                                      \
        for (int fi = 0; fi < 4; ++fi)                                         \
            afr[fi] = *(const bf16x8*)(cbuf + aoff[fi]);                       \
        __builtin_amdgcn_s_barrier();                                          \
        __builtin_amdgcn_s_setprio(1);                                         \
        MFMA16(0, afr, bfr);                                                   \
        __builtin_amdgcn_s_setprio(0);                                         \
        __builtin_amdgcn_s_barrier();                                          \
        /* phase B: issue B(T+3) gloads; read high A frags */                  \
        if (SB) { GLOAD_B((T) + 3, bbuf); }                                    \
        bf16x8 af2[4];                                                         \
        _Pragma("unroll")                                                      \
        for (int fi = 0; fi < 4; ++fi)                                         \
            af2[fi] = *(const bf16x8*)(cbuf + aoff[4 + fi]);                   \
        __builtin_amdgcn_s_barrier();                                          \
        __builtin_amdgcn_s_setprio(1);                                         \
        MFMA16(4, af2, bfr);                                                   \
        __builtin_amdgcn_s_setprio(0);                                         \
        /* cvt A(T+2) into abuf (linear dests; implicit wait on avA) */        \
        if (SA) { CVT_A(abuf); }                                               \
        asm volatile("s_waitcnt vmcnt(" #WN ")" ::: "memory");                 \
        asm volatile("s_waitcnt lgkmcnt(0)" ::: "memory");                     \
        __builtin_amdgcn_s_barrier();                                          \
    } while (0)

    // steady: T=0..28 (A up to 30, B up to 31); vmcnt(2) = B(T+3) in flight
    for (int t = 0; t < NT - 3; ++t) {
        KTILE(t, 1, 1, 2);
    }
    // T=29: stage A(31) only; boundary needs B(30): outstanding B(31)x2
    KTILE(29, 1, 0, 2);
    // T=30: boundary needs B(31)
    KTILE(30, 0, 0, 0);
    KTILE(31, 0, 0, 0);
#undef KTILE
#undef MFMA16
#undef GLOAD_B
#undef CVT_A
#undef LOAD_A

    // epilogue: + bias, leaky_relu, fp32 store
    #pragma unroll
    for (int fi = 0; fi < 8; ++fi)
        #pragma unroll
        for (int fj = 0; fj < 4; ++fj) {
            const int col = nt * 256 + wn * 64 + fj * 16 + lr;
            const float b = bcomb[col];
            #pragma unroll
            for (int r = 0; r < 4; ++r) {
                const int row = mt * 256 + wm * 128 + fi * 16 + lk * 4 + r;
                float v = acc[fi][fj][r] + b;
                out[(size_t)row * NDIM + col] = v >= 0.f ? v : 0.01f * v;
            }
        }
}

// ---------------------------------------------------------------------------
// Fallback main GEMM (fused fp32->bf16 A path, 128x128) if ws is too small.
// ---------------------------------------------------------------------------
__global__ __launch_bounds__(256) void main_gemm_f32(
    const float* __restrict__ X, const unsigned short* __restrict__ Wc,
    const float* __restrict__ bcomb, float* __restrict__ out) {
    __shared__ unsigned short As[128 * 32];
    __shared__ unsigned short Bs[128 * 32];
    const int t = threadIdx.x;
    const int nt = blockIdx.x & 7;
    const int mt = blockIdx.x >> 3;
    const int w = t >> 6, l = t & 63;
    const int wr = (w >> 1) * 64, wcc = (w & 1) * 64;
    const int lr = l & 15, lk = l >> 4;

    f32x4 acc[4][4] = {};

    const int arow = t >> 3;
    const int akq = t & 7;
    const int brow = t >> 2;
    const int bc4 = t & 3;

    for (int kt = 0; kt < KDIM / 32; ++kt) {
        float4 av[4];
        #pragma unroll
        for (int j = 0; j < 4; ++j) {
            const int row = j * 32 + arow;
            av[j] = *(const float4*)&X[(mt * 128 + row) * KDIM + kt * 32 + akq * 4];
        }
        __syncthreads();
        #pragma unroll
        for (int j = 0; j < 4; ++j) {
            const int row = j * 32 + arow;
            u16x4 p = { f2bf(av[j].x), f2bf(av[j].y), f2bf(av[j].z), f2bf(av[j].w) };
            *(u16x4*)&As[row * 32 + akq * 4] = p;
        }
        #pragma unroll
        for (int j = 0; j < 2; ++j) {
            const int row = j * 64 + brow;
            const unsigned short* g = &Wc[(nt * 128 + row) * KDIM + kt * 32 + bc4 * 8];
            unsigned short* ldst = &Bs[(j * 256 + w * 64) * 8];
            gload16(g, ldst);
        }
        __syncthreads();
        bf16x8 af[4], bfr[4];
        #pragma unroll
        for (int fi = 0; fi < 4; ++fi)
            af[fi] = *(bf16x8*)&As[(wr + fi * 16 + lr) * 32 + lk * 8];
        #pragma unroll
        for (int fj = 0; fj < 4; ++fj)
            bfr[fj] = *(bf16x8*)&Bs[(wcc + fj * 16 + lr) * 32 + lk * 8];
        #pragma unroll
        for (int fi = 0; fi < 4; ++fi)
            #pragma unroll
            for (int fj = 0; fj < 4; ++fj)
                acc[fi][fj] = __builtin_amdgcn_mfma_f32_16x16x32_bf16(
                    af[fi], bfr[fj], acc[fi][fj], 0, 0, 0);
    }

    #pragma unroll
    for (int fi = 0; fi < 4; ++fi)
        #pragma unroll
        for (int fj = 0; fj < 4; ++fj) {
            const int col = nt * 128 + wcc + fj * 16 + lr;
            const float b = bcomb[col];
            #pragma unroll
            for (int r = 0; r < 4; ++r) {
                const int row = mt * 128 + wr + fi * 16 + lk * 4 + r;
                float v = acc[fi][fj][r] + b;
                out[row * NDIM + col] = v >= 0.f ? v : 0.01f * v;
            }
        }
}

extern "C" void kernel_launch(void* const* d_in, const int* in_sizes, int n_in,
                              void* d_out, int out_size, void* d_ws, size_t ws_size,
                              hipStream_t stream) {
    const float* xs   = (const float*)d_in[0];
    // d_in[1] mask unused: softmax row-sums are exactly 1.
    const float* Wv   = (const float*)d_in[6];
    const float* bv   = (const float*)d_in[7];
    const float* Wlin = (const float*)d_in[8];
    const float* blin = (const float*)d_in[9];

    unsigned short* Wc = (unsigned short*)d_ws;                         // 2 MB
    float* bcomb = (float*)((char*)d_ws + 2097152);                     // 4 KB
    float* out = (float*)d_out;

    // transient scratch in d_out (64 MB, fully overwritten by the final GEMM)
    unsigned short* Wvt = (unsigned short*)d_out;                       // 2 MB
    unsigned short* Wlb = (unsigned short*)((char*)d_out + 2097152);    // 2 MB

    const size_t NEED = 2101248;
    hipLaunchKernelGGL(prep0_kernel, dim3(768), dim3(256), 0, stream,
                       Wv, Wlin, bv, blin, Wvt, Wlb, bcomb);
    hipLaunchKernelGGL(wcomb_kernel, dim3(256), dim3(256), 0, stream,
                       Wlb, Wvt, Wc);
    if (ws_size >= NEED) {
        (void)hipFuncSetAttribute((const void*)main_fused,
                                  hipFuncAttributeMaxDynamicSharedMemorySize,
                                  131072);
        hipLaunchKernelGGL(main_fused, dim3(256), dim3(512), 131072, stream,
                           xs, Wc, bcomb, out);
    } else {
        hipLaunchKernelGGL(main_gemm_f32, dim3((M_TOT / 128) * (NDIM / 128)),
                           dim3(256), 0, stream, xs, Wc, bcomb, out);
    }
}